// Round 1
// baseline (3615.505 us; speedup 1.0000x reference)
//
#include <hip/hip_runtime.h>
#include <stdint.h>
#include <math.h>

// Problem constants (fixed by reference setup_inputs)
#define B_SZ   32
#define T_LEN  2048
#define DIN    512
#define DD     512
#define BM     16          // rows (b,t) per workgroup; 2048 % 16 == 0 -> one b per tile
#define NTHREADS 256

// ---------------------------------------------------------------------------
// Threefry-2x32 (20 rounds), bit-exact vs JAX's threefry2x32 primitive.
// ---------------------------------------------------------------------------
__device__ __forceinline__ uint32_t rotl32(uint32_t x, int n) {
  return (x << n) | (x >> (32 - n));
}

__device__ __forceinline__ void threefry2x32(uint32_t k0, uint32_t k1,
                                             uint32_t x0, uint32_t x1,
                                             uint32_t& o0, uint32_t& o1) {
  const uint32_t ks0 = k0, ks1 = k1, ks2 = k0 ^ k1 ^ 0x1BD11BDAu;
  uint32_t v0 = x0 + ks0, v1 = x1 + ks1;
#define TF_R(r) { v0 += v1; v1 = rotl32(v1, (r)); v1 ^= v0; }
  TF_R(13) TF_R(15) TF_R(26) TF_R(6)
  v0 += ks1; v1 += ks2 + 1u;
  TF_R(17) TF_R(29) TF_R(16) TF_R(24)
  v0 += ks2; v1 += ks0 + 2u;
  TF_R(13) TF_R(15) TF_R(26) TF_R(6)
  v0 += ks0; v1 += ks1 + 3u;
  TF_R(17) TF_R(29) TF_R(16) TF_R(24)
  v0 += ks1; v1 += ks2 + 4u;
  TF_R(13) TF_R(15) TF_R(26) TF_R(6)
  v0 += ks2; v1 += ks0 + 5u;
#undef TF_R
  o0 = v0; o1 = v1;
}

// JAX partitionable random_bits(32) at flat index idx under key (ka,kb):
// counter = (hi=0, lo=idx); bits = out0 ^ out1; uniform = f32 trick.
__device__ __forceinline__ float u01_from_key(uint32_t ka, uint32_t kb, uint32_t idx) {
  uint32_t r0, r1;
  threefry2x32(ka, kb, 0u, idx, r0, r1);
  uint32_t bits = r0 ^ r1;
  return __uint_as_float((bits >> 9) | 0x3F800000u) - 1.0f;
}

__device__ __forceinline__ float sigmoidf_(float x) {
  return 1.0f / (1.0f + __expf(-x));
}

// ---------------------------------------------------------------------------
// Kernel 1: dropout masks.
// noise_i[B,DIN]: bernoulli(k1, keep=0.25)/0.25   -> {0, 4}
// noise_s[B,DD] : bernoulli(k2, keep=0.75)/0.75   -> {0, 4/3}
// k1,k2 = partitionable split of key(seed=42) = threefry((0,42),(0,{0,1}))
// ---------------------------------------------------------------------------
__global__ void noise_kernel(float* __restrict__ noise_i, float* __restrict__ noise_s) {
  int i = blockIdx.x * blockDim.x + threadIdx.x;
  if (i >= B_SZ * DIN) return;
  uint32_t k1a, k1b, k2a, k2b;
  threefry2x32(0u, 42u, 0u, 0u, k1a, k1b);
  threefry2x32(0u, 42u, 0u, 1u, k2a, k2b);
  float ui = u01_from_key(k1a, k1b, (uint32_t)i);
  noise_i[i] = (ui < 0.25f) ? 4.0f : 0.0f;
  float us = u01_from_key(k2a, k2b, (uint32_t)i);
  noise_s[i] = (us < 0.75f) ? (1.0f / 0.75f) : 0.0f;
}

// ---------------------------------------------------------------------------
// Kernel 2: layer-0 state projections (rank-1 over (b,d), t-independent):
// vH0[b,c] = sum_k h0[k]*noise_s[b,k]*recurH_w[0][k,c] + recurH_b[0][c]
// ---------------------------------------------------------------------------
__global__ void vec0_kernel(const float* __restrict__ h0,
                            const float* __restrict__ noise_s,
                            const float* __restrict__ rHw, const float* __restrict__ rHb,
                            const float* __restrict__ rTw, const float* __restrict__ rTb,
                            float* __restrict__ vH0, float* __restrict__ vT0) {
  int b = blockIdx.x;
  int c = threadIdx.x;
  float aH = 0.f, aT = 0.f;
  const float* ns = noise_s + b * DD;
  for (int k = 0; k < DD; ++k) {
    float sdv = h0[k] * ns[k];
    aH += sdv * rHw[(size_t)k * DD + c];
    aT += sdv * rTw[(size_t)k * DD + c];
  }
  vH0[b * DD + c] = aH + rHb[c];
  vT0[b * DD + c] = aT + rTb[c];
}

// ---------------------------------------------------------------------------
// Fused main kernel: per 16-row tile, 3 GEMM-pairs (H&T share LDS reads) +
// highway combines; s carried in registers; noised s round-trips through LDS.
// Thread micro-tile: 4 rows x 8 cols (cols c0..c0+3 and c0+256..c0+259).
// ---------------------------------------------------------------------------
__device__ __forceinline__ void gemm_pair(const float (*sX)[DD],
                                          const float* __restrict__ WH,
                                          const float* __restrict__ WT,
                                          int r0, int c0,
                                          float accH[4][8], float accT[4][8]) {
#pragma unroll
  for (int i = 0; i < 4; ++i)
#pragma unroll
    for (int j = 0; j < 8; ++j) { accH[i][j] = 0.f; accT[i][j] = 0.f; }

  for (int k4 = 0; k4 < DD / 4; ++k4) {
    float4 sv0 = *(const float4*)&sX[r0 + 0][k4 * 4];
    float4 sv1 = *(const float4*)&sX[r0 + 1][k4 * 4];
    float4 sv2 = *(const float4*)&sX[r0 + 2][k4 * 4];
    float4 sv3 = *(const float4*)&sX[r0 + 3][k4 * 4];
    float a0[4] = {sv0.x, sv0.y, sv0.z, sv0.w};
    float a1[4] = {sv1.x, sv1.y, sv1.z, sv1.w};
    float a2[4] = {sv2.x, sv2.y, sv2.z, sv2.w};
    float a3[4] = {sv3.x, sv3.y, sv3.z, sv3.w};
#pragma unroll
    for (int j = 0; j < 4; ++j) {
      int k = k4 * 4 + j;
      const float* rowH = WH + (size_t)k * DD;
      const float* rowT = WT + (size_t)k * DD;
      float4 wh0 = *(const float4*)(rowH + c0);
      float4 wh1 = *(const float4*)(rowH + c0 + 256);
      float4 wt0 = *(const float4*)(rowT + c0);
      float4 wt1 = *(const float4*)(rowT + c0 + 256);
      float a[4] = {a0[j], a1[j], a2[j], a3[j]};
#pragma unroll
      for (int i = 0; i < 4; ++i) {
        accH[i][0] += a[i] * wh0.x; accH[i][1] += a[i] * wh0.y;
        accH[i][2] += a[i] * wh0.z; accH[i][3] += a[i] * wh0.w;
        accH[i][4] += a[i] * wh1.x; accH[i][5] += a[i] * wh1.y;
        accH[i][6] += a[i] * wh1.z; accH[i][7] += a[i] * wh1.w;
        accT[i][0] += a[i] * wt0.x; accT[i][1] += a[i] * wt0.y;
        accT[i][2] += a[i] * wt0.z; accT[i][3] += a[i] * wt0.w;
        accT[i][4] += a[i] * wt1.x; accT[i][5] += a[i] * wt1.y;
        accT[i][6] += a[i] * wt1.z; accT[i][7] += a[i] * wt1.w;
      }
    }
  }
}

__global__ __launch_bounds__(NTHREADS) void rhn_main(
    const float* __restrict__ h0,
    const float* __restrict__ seq,
    const float* __restrict__ wH, const float* __restrict__ bH,
    const float* __restrict__ wT, const float* __restrict__ bT,
    const float* __restrict__ rHw, const float* __restrict__ rHb,
    const float* __restrict__ rTw, const float* __restrict__ rTb,
    const float* __restrict__ noise_i, const float* __restrict__ noise_s,
    const float* __restrict__ vH0, const float* __restrict__ vT0,
    float* __restrict__ out) {
  __shared__ float sX[BM][DD];

  const int wg = blockIdx.x;
  const int g0 = wg * BM;           // first flat (b,t) row of tile
  const int b  = g0 / T_LEN;        // whole tile shares one b
  const int tid = threadIdx.x;
  const int ty = tid >> 6;          // 0..3
  const int tx = tid & 63;          // 0..63
  const int r0 = ty * 4;
  const int c0 = tx * 4;            // cols c0..c0+3 and c0+256..c0+259

  // Stage x = seq * noise_i into LDS (float4, coalesced).
  {
    const float* seqRow = seq + (size_t)g0 * DIN;
    const float* ni = noise_i + b * DIN;
    for (int idx = tid; idx < BM * (DIN / 4); idx += NTHREADS) {
      int r  = idx >> 7;          // / (DIN/4)
      int c4 = idx & 127;
      float4 v = *(const float4*)(seqRow + (size_t)r * DIN + c4 * 4);
      float4 n = *(const float4*)(ni + c4 * 4);
      v.x *= n.x; v.y *= n.y; v.z *= n.z; v.w *= n.w;
      *(float4*)&sX[r][c4 * 4] = v;
    }
  }
  __syncthreads();

  float accH[4][8], accT[4][8], sReg[4][8];
  const float* nsb = noise_s + b * DD;

  // ---- input projections: i_H = x@wH, i_T = x@wT (biases added in combine)
  gemm_pair(sX, wH, wT, r0, c0, accH, accT);
  __syncthreads();   // all reads of sX done before overwrite

  // ---- layer 0 combine: h = vH0 + bH + i_H ; t = vT0 + bT + i_T ; s0 = h0
#pragma unroll
  for (int g = 0; g < 2; ++g) {
#pragma unroll
    for (int q = 0; q < 4; ++q) {
      int c  = c0 + g * 256 + q;
      int cc = g * 4 + q;
      float h0c = h0[c];
      float vh  = vH0[b * DD + c] + bH[c];
      float vt  = vT0[b * DD + c] + bT[c];
      float nsc = nsb[c];
#pragma unroll
      for (int i = 0; i < 4; ++i) {
        float hg = tanhf(accH[i][cc] + vh);
        float tg = sigmoidf_(accT[i][cc] + vt);
        float sn = (hg - h0c) * tg + h0c;
        sReg[i][cc] = sn;
        sX[r0 + i][c] = sn * nsc;   // noised state for next GEMM
      }
    }
  }
  __syncthreads();

  // ---- layer 1
  gemm_pair(sX, rHw + (size_t)DD * DD, rTw + (size_t)DD * DD, r0, c0, accH, accT);
  __syncthreads();
#pragma unroll
  for (int g = 0; g < 2; ++g) {
#pragma unroll
    for (int q = 0; q < 4; ++q) {
      int c  = c0 + g * 256 + q;
      int cc = g * 4 + q;
      float hb  = rHb[DD + c];
      float tb  = rTb[DD + c];
      float nsc = nsb[c];
#pragma unroll
      for (int i = 0; i < 4; ++i) {
        float hg = tanhf(accH[i][cc] + hb);
        float tg = sigmoidf_(accT[i][cc] + tb);
        float sp = sReg[i][cc];
        float sn = (hg - sp) * tg + sp;
        sReg[i][cc] = sn;
        sX[r0 + i][c] = sn * nsc;
      }
    }
  }
  __syncthreads();

  // ---- layer 2 + store
  gemm_pair(sX, rHw + (size_t)2 * DD * DD, rTw + (size_t)2 * DD * DD, r0, c0, accH, accT);
#pragma unroll
  for (int i = 0; i < 4; ++i) {
    float o0[4], o1[4];
#pragma unroll
    for (int g = 0; g < 2; ++g) {
#pragma unroll
      for (int q = 0; q < 4; ++q) {
        int c  = c0 + g * 256 + q;
        int cc = g * 4 + q;
        float hg = tanhf(accH[i][cc] + rHb[2 * DD + c]);
        float tg = sigmoidf_(accT[i][cc] + rTb[2 * DD + c]);
        float sp = sReg[i][cc];
        float sn = (hg - sp) * tg + sp;
        if (g == 0) o0[q] = sn; else o1[q] = sn;
      }
    }
    size_t rowoff = (size_t)(g0 + r0 + i) * DD;
    float4 v0 = {o0[0], o0[1], o0[2], o0[3]};
    float4 v1 = {o1[0], o1[1], o1[2], o1[3]};
    *(float4*)(out + rowoff + c0)       = v0;
    *(float4*)(out + rowoff + c0 + 256) = v1;
  }
}

// ---------------------------------------------------------------------------
extern "C" void kernel_launch(void* const* d_in, const int* in_sizes, int n_in,
                              void* d_out, int out_size, void* d_ws, size_t ws_size,
                              hipStream_t stream) {
  const float* h0  = (const float*)d_in[0];
  const float* seq = (const float*)d_in[1];
  const float* wH  = (const float*)d_in[2];
  const float* bH  = (const float*)d_in[3];
  const float* wT  = (const float*)d_in[4];
  const float* bT  = (const float*)d_in[5];
  const float* rHw = (const float*)d_in[6];
  const float* rHb = (const float*)d_in[7];
  const float* rTw = (const float*)d_in[8];
  const float* rTb = (const float*)d_in[9];
  float* out = (float*)d_out;

  float* ws = (float*)d_ws;
  float* noise_i = ws;              // 16384 f32
  float* noise_s = ws + 16384;      // 16384 f32
  float* vH0     = ws + 32768;      // 16384 f32
  float* vT0     = ws + 49152;      // 16384 f32  (total 256 KiB of d_ws)

  noise_kernel<<<(B_SZ * DIN + 255) / 256, 256, 0, stream>>>(noise_i, noise_s);
  vec0_kernel<<<B_SZ, DD, 0, stream>>>(h0, noise_s, rHw, rHb, rTw, rTb, vH0, vT0);
  rhn_main<<<(B_SZ * T_LEN) / BM, NTHREADS, 0, stream>>>(
      h0, seq, wH, bH, wT, bT, rHw, rHb, rTw, rTb,
      noise_i, noise_s, vH0, vT0, out);
}

// Round 2
// 1085.844 us; speedup vs baseline: 3.3297x; 3.3297x over previous
//
#include <hip/hip_runtime.h>
#include <stdint.h>
#include <math.h>

// Problem constants (fixed by reference setup_inputs)
#define B_SZ   32
#define T_LEN  2048
#define DIN    512
#define DD     512
#define M_TOT  (B_SZ * T_LEN)   // 65536 rows
#define NTHREADS 256

typedef unsigned short u16;
typedef __attribute__((ext_vector_type(8))) short short8;
typedef __attribute__((ext_vector_type(4))) float f32x4;

// ---------------------------------------------------------------------------
// fp32 -> bf16 round-to-nearest-even
// ---------------------------------------------------------------------------
__device__ __forceinline__ u16 f2bf(float f) {
  uint32_t u = __float_as_uint(f);
  uint32_t r = (u + 0x7FFFu + ((u >> 16) & 1u)) >> 16;
  return (u16)r;
}

// async global->LDS, 16B per lane; LDS dest = wave-uniform base + lane*16
typedef const void __attribute__((address_space(1)))* as1cp;
typedef void __attribute__((address_space(3)))* as3p;
__device__ __forceinline__ void async16(const void* g, void* l) {
  __builtin_amdgcn_global_load_lds((as1cp)(uintptr_t)g,
                                   (as3p)(uint32_t)(uintptr_t)l, 16, 0, 0);
}

// ---------------------------------------------------------------------------
// Threefry-2x32 (20 rounds), bit-exact vs JAX's threefry2x32 primitive.
// ---------------------------------------------------------------------------
__device__ __forceinline__ uint32_t rotl32(uint32_t x, int n) {
  return (x << n) | (x >> (32 - n));
}

__device__ __forceinline__ void threefry2x32(uint32_t k0, uint32_t k1,
                                             uint32_t x0, uint32_t x1,
                                             uint32_t& o0, uint32_t& o1) {
  const uint32_t ks0 = k0, ks1 = k1, ks2 = k0 ^ k1 ^ 0x1BD11BDAu;
  uint32_t v0 = x0 + ks0, v1 = x1 + ks1;
#define TF_R(r) { v0 += v1; v1 = rotl32(v1, (r)); v1 ^= v0; }
  TF_R(13) TF_R(15) TF_R(26) TF_R(6)
  v0 += ks1; v1 += ks2 + 1u;
  TF_R(17) TF_R(29) TF_R(16) TF_R(24)
  v0 += ks2; v1 += ks0 + 2u;
  TF_R(13) TF_R(15) TF_R(26) TF_R(6)
  v0 += ks0; v1 += ks1 + 3u;
  TF_R(17) TF_R(29) TF_R(16) TF_R(24)
  v0 += ks1; v1 += ks2 + 4u;
  TF_R(13) TF_R(15) TF_R(26) TF_R(6)
  v0 += ks2; v1 += ks0 + 5u;
#undef TF_R
  o0 = v0; o1 = v1;
}

__device__ __forceinline__ float u01_from_key(uint32_t ka, uint32_t kb, uint32_t idx) {
  uint32_t r0, r1;
  threefry2x32(ka, kb, 0u, idx, r0, r1);
  uint32_t bits = r0 ^ r1;
  return __uint_as_float((bits >> 9) | 0x3F800000u) - 1.0f;
}

__global__ void noise_kernel(float* __restrict__ noise_i, float* __restrict__ noise_s) {
  int i = blockIdx.x * blockDim.x + threadIdx.x;
  if (i >= B_SZ * DIN) return;
  uint32_t k1a, k1b, k2a, k2b;
  threefry2x32(0u, 42u, 0u, 0u, k1a, k1b);
  threefry2x32(0u, 42u, 0u, 1u, k2a, k2b);
  float ui = u01_from_key(k1a, k1b, (uint32_t)i);
  noise_i[i] = (ui < 0.25f) ? 4.0f : 0.0f;
  float us = u01_from_key(k2a, k2b, (uint32_t)i);
  noise_s[i] = (us < 0.75f) ? (1.0f / 0.75f) : 0.0f;
}

// layer-0 state projections, exact fp32 (t-independent):
// vH0[b,c] = sum_k h0[k]*noise_s[b,k]*recurH_w[0][k,c] + recurH_b[0][c]
__global__ void vec0_kernel(const float* __restrict__ h0,
                            const float* __restrict__ noise_s,
                            const float* __restrict__ rHw, const float* __restrict__ rHb,
                            const float* __restrict__ rTw, const float* __restrict__ rTb,
                            float* __restrict__ vH0, float* __restrict__ vT0) {
  int b = blockIdx.x;
  int c = threadIdx.x;
  float aH = 0.f, aT = 0.f;
  const float* ns = noise_s + b * DD;
  for (int k = 0; k < DD; ++k) {
    float sdv = h0[k] * ns[k];
    aH += sdv * rHw[(size_t)k * DD + c];
    aT += sdv * rTw[(size_t)k * DD + c];
  }
  vH0[b * DD + c] = aH + rHb[c];
  vT0[b * DD + c] = aT + rTb[c];
}

// ---------------------------------------------------------------------------
// Transpose+convert one 512x512 fp32 W[k][n] -> bf16 Wt[n][k]
// 64x64 tiles, LDS staged; grid = 64 blocks.
// ---------------------------------------------------------------------------
__global__ __launch_bounds__(256) void wt_kernel(const float* __restrict__ W,
                                                 u16* __restrict__ Wt) {
  __shared__ float tile[64][68];
  const int kt = (blockIdx.x >> 3) * 64;
  const int nt = (blockIdx.x & 7) * 64;
  const int tid = threadIdx.x;
  {
    int r = tid >> 2;
#pragma unroll
    for (int u = 0; u < 4; ++u) {
      int c = ((tid & 3) + u * 4) * 4;
      float4 v = *(const float4*)(W + (size_t)(kt + r) * DD + nt + c);
      tile[r][c] = v.x; tile[r][c + 1] = v.y; tile[r][c + 2] = v.z; tile[r][c + 3] = v.w;
    }
  }
  __syncthreads();
  {
    int n = tid >> 2, seg = (tid & 3) * 16;
    u16 o[16];
#pragma unroll
    for (int u = 0; u < 16; ++u) o[u] = f2bf(tile[seg + u][n]);
    *(uint4*)(Wt + (size_t)(nt + n) * DD + kt + seg) = *(const uint4*)o;
    *(uint4*)(Wt + (size_t)(nt + n) * DD + kt + seg + 8) = *(const uint4*)(o + 8);
  }
}

// ---------------------------------------------------------------------------
// Xbf[m][k] = bf16(seq[m][k] * noise_i[b][k]);  one thread per 8 elements.
// ---------------------------------------------------------------------------
__global__ __launch_bounds__(256) void xprep(const float* __restrict__ seq,
                                             const float* __restrict__ noise_i,
                                             u16* __restrict__ Xbf) {
  int idx = blockIdx.x * 256 + threadIdx.x;   // 4,194,304 granules of 8
  int row = idx >> 6;
  int k8 = (idx & 63) * 8;
  int b = row >> 11;
  const float* s = seq + (size_t)row * DIN + k8;
  const float* n = noise_i + b * DIN + k8;
  float4 s0 = *(const float4*)s, s1 = *(const float4*)(s + 4);
  float4 n0 = *(const float4*)n, n1 = *(const float4*)(n + 4);
  u16 o[8];
  o[0] = f2bf(s0.x * n0.x); o[1] = f2bf(s0.y * n0.y);
  o[2] = f2bf(s0.z * n0.z); o[3] = f2bf(s0.w * n0.w);
  o[4] = f2bf(s1.x * n1.x); o[5] = f2bf(s1.y * n1.y);
  o[6] = f2bf(s1.z * n1.z); o[7] = f2bf(s1.w * n1.w);
  *(uint4*)(Xbf + (size_t)idx * 8) = *(const uint4*)o;
}

// ---------------------------------------------------------------------------
// Fused layer GEMM: C_tile 128m x 128n, K=512 in 8 chunks of 64.
// Dual accumulators (H and T) share A-fragments. XOR-swizzled LDS so that
// global_load_lds staging is contiguous AND frag ds_read_b128 is conflict-free.
// Epilogue: highway combine, write S (fp32) + SD (bf16) or final out.
// ---------------------------------------------------------------------------
__global__ __launch_bounds__(256) void layer_gemm(
    const u16* __restrict__ Abf,    // [65536][512] bf16 (X' or SD)
    const u16* __restrict__ WtH,    // [512 n][512 k] bf16
    const u16* __restrict__ WtT,
    const float* __restrict__ hbv,  // [512] H bias vec (bH or rHb[l])
    const float* __restrict__ tbv,  // [512] T bias vec
    const float* __restrict__ vH0,  // [32][512] (layer0) or null
    const float* __restrict__ vT0,
    const float* __restrict__ h0,   // [512]
    const float* __restrict__ noise_s, // [32][512]
    const float* Sprev,             // fp32, null for layer0 (may alias Snew/Out)
    float* Snew,                    // fp32 (layers 0,1)
    u16* __restrict__ SDnew,        // bf16 (layers 0,1)
    float* Out,                     // fp32 (layer2)
    int layer) {
  __shared__ u16 lds[24576];        // A:8192, BH:8192, BT:8192 (48 KiB)
  u16* ldsA  = lds;
  u16* ldsBH = lds + 8192;
  u16* ldsBT = lds + 16384;

  const int tid  = threadIdx.x;
  const int lane = tid & 63, wid = tid >> 6;
  const int bid  = blockIdx.x;
  const int m0   = (bid >> 2) * 128;
  const int c0   = (bid & 3) * 128;
  const int bidx = m0 >> 11;            // batch index (tile never crosses b)
  const int q  = lane >> 4, mr = lane & 15;
  const int wqm = wid >> 1, wqn = wid & 1;

  // Per-lane staging addresses. LDS slot s (16B) holds granule (row=s>>3,
  // k8 = (s&7) ^ (row&7)) of the current k-chunk.
  const u16* gA[4]; const u16* gBH[4]; const u16* gBT[4];
  u16* lA[4]; u16* lBH[4]; u16* lBT[4];
#pragma unroll
  for (int t = 0; t < 4; ++t) {
    int s  = wid * 256 + t * 64 + lane;
    int rm = s >> 3;
    int k8 = (s & 7) ^ (rm & 7);
    gA[t]  = Abf + (size_t)(m0 + rm) * DD + k8 * 8;
    gBH[t] = WtH + (size_t)(c0 + rm) * DD + k8 * 8;
    gBT[t] = WtT + (size_t)(c0 + rm) * DD + k8 * 8;
    int lofs = (wid * 256 + t * 64) * 8;
    lA[t] = ldsA + lofs; lBH[t] = ldsBH + lofs; lBT[t] = ldsBT + lofs;
  }

  f32x4 accH[4][4], accT[4][4];
#pragma unroll
  for (int i = 0; i < 4; ++i)
#pragma unroll
    for (int j = 0; j < 4; ++j) {
      accH[i][j] = (f32x4){0.f, 0.f, 0.f, 0.f};
      accT[i][j] = (f32x4){0.f, 0.f, 0.f, 0.f};
    }

  for (int kb = 0; kb < 8; ++kb) {
    __syncthreads();                 // prior chunk's LDS reads complete
    const int ko = kb * 64;          // k advance in elements (=128B)
#pragma unroll
    for (int t = 0; t < 4; ++t) {
      async16(gA[t] + ko,  lA[t]);
      async16(gBH[t] + ko, lBH[t]);
      async16(gBT[t] + ko, lBT[t]);
    }
    __syncthreads();                 // drains vmcnt: LDS filled

#pragma unroll
    for (int ks = 0; ks < 2; ++ks) {
      const int jj = ((((ks << 2) + q) ^ (mr & 7)) << 3); // u16 offset in row
      short8 a[4];
#pragma unroll
      for (int mt = 0; mt < 4; ++mt)
        a[mt] = *(const short8*)(ldsA + (wqm * 64 + mt * 16 + mr) * 64 + jj);
#pragma unroll
      for (int nt = 0; nt < 4; ++nt) {
        int nofs = (wqn * 64 + nt * 16 + mr) * 64 + jj;
        short8 bh = *(const short8*)(ldsBH + nofs);
        short8 bt = *(const short8*)(ldsBT + nofs);
#pragma unroll
        for (int mt = 0; mt < 4; ++mt) {
          accH[mt][nt] = __builtin_amdgcn_mfma_f32_16x16x32_bf16(a[mt], bh, accH[mt][nt], 0, 0, 0);
          accT[mt][nt] = __builtin_amdgcn_mfma_f32_16x16x32_bf16(a[mt], bt, accT[mt][nt], 0, 0, 0);
        }
      }
    }
  }

  // Epilogue. C/D layout: col = lane&15, row = (lane>>4)*4 + reg.
  const int b512 = bidx * DD;
#pragma unroll
  for (int nt = 0; nt < 4; ++nt) {
    const int gc = c0 + wqn * 64 + nt * 16 + mr;
    float hb = hbv[gc], tb = tbv[gc];
    float nsc = 0.f, h0c = 0.f;
    if (layer == 0) {
      hb += vH0[b512 + gc];
      tb += vT0[b512 + gc];
      h0c = h0[gc];
    }
    if (layer < 2) nsc = noise_s[b512 + gc];
#pragma unroll
    for (int mt = 0; mt < 4; ++mt) {
      const int gmb = m0 + wqm * 64 + mt * 16 + q * 4;
#pragma unroll
      for (int r = 0; r < 4; ++r) {
        const size_t o = (size_t)(gmb + r) * DD + gc;
        float sp = (layer == 0) ? h0c : Sprev[o];
        float hg = tanhf(accH[mt][nt][r] + hb);
        float tg = 1.f / (1.f + __expf(-(accT[mt][nt][r] + tb)));
        float sn = (hg - sp) * tg + sp;
        if (layer < 2) {
          Snew[o] = sn;
          SDnew[o] = f2bf(sn * nsc);
        } else {
          Out[o] = sn;
        }
      }
    }
  }
}

// ---------------------------------------------------------------------------
extern "C" void kernel_launch(void* const* d_in, const int* in_sizes, int n_in,
                              void* d_out, int out_size, void* d_ws, size_t ws_size,
                              hipStream_t stream) {
  const float* h0  = (const float*)d_in[0];
  const float* seq = (const float*)d_in[1];
  const float* wH  = (const float*)d_in[2];
  const float* bH  = (const float*)d_in[3];
  const float* wT  = (const float*)d_in[4];
  const float* bT  = (const float*)d_in[5];
  const float* rHw = (const float*)d_in[6];
  const float* rHb = (const float*)d_in[7];
  const float* rTw = (const float*)d_in[8];
  const float* rTb = (const float*)d_in[9];
  float* out = (float*)d_out;

  char* ws = (char*)d_ws;
  float* noise_i = (float*)(ws);                       // 64 KB
  float* noise_s = (float*)(ws + (64 << 10));          // 64 KB
  float* vH0     = (float*)(ws + (128 << 10));         // 64 KB
  float* vT0     = (float*)(ws + (192 << 10));         // 64 KB
  u16* WtwH  = (u16*)(ws + (256 << 10));               // 512 KB each
  u16* WtwT  = WtwH + (size_t)DD * DD;
  u16* Wt1H  = WtwT + (size_t)DD * DD;
  u16* Wt2H  = Wt1H + (size_t)DD * DD;
  u16* Wt1T  = Wt2H + (size_t)DD * DD;
  u16* Wt2T  = Wt1T + (size_t)DD * DD;
  u16* Xbf   = (u16*)(ws + (4ull << 20));              // 64 MB (also SD1)
  u16* SD0   = (u16*)(ws + (68ull << 20));             // 64 MB

  const size_t WSZ = (size_t)DD * DD;

  noise_kernel<<<(B_SZ * DIN + 255) / 256, 256, 0, stream>>>(noise_i, noise_s);
  vec0_kernel<<<B_SZ, DD, 0, stream>>>(h0, noise_s, rHw, rHb, rTw, rTb, vH0, vT0);
  wt_kernel<<<64, 256, 0, stream>>>(wH, WtwH);
  wt_kernel<<<64, 256, 0, stream>>>(wT, WtwT);
  wt_kernel<<<64, 256, 0, stream>>>(rHw + WSZ,     Wt1H);
  wt_kernel<<<64, 256, 0, stream>>>(rHw + 2 * WSZ, Wt2H);
  wt_kernel<<<64, 256, 0, stream>>>(rTw + WSZ,     Wt1T);
  wt_kernel<<<64, 256, 0, stream>>>(rTw + 2 * WSZ, Wt2T);
  xprep<<<M_TOT * DIN / 8 / 256, 256, 0, stream>>>(seq, noise_i, Xbf);

  const int NBLK = (M_TOT / 128) * (DD / 128);   // 2048
  // Layer 0: A=Xbf, S->out, SD->SD0
  layer_gemm<<<NBLK, NTHREADS, 0, stream>>>(
      Xbf, WtwH, WtwT, bH, bT, vH0, vT0, h0, noise_s,
      nullptr, out, SD0, nullptr, 0);
  // Layer 1: A=SD0, Sprev=out, S->out (in place, disjoint per element), SD->Xbf
  layer_gemm<<<NBLK, NTHREADS, 0, stream>>>(
      SD0, Wt1H, Wt1T, rHb + DD, rTb + DD, nullptr, nullptr, h0, noise_s,
      out, out, Xbf, nullptr, 1);
  // Layer 2: A=Xbf(SD1), Sprev=out, final -> out
  layer_gemm<<<NBLK, NTHREADS, 0, stream>>>(
      Xbf, Wt2H, Wt2T, rHb + 2 * DD, rTb + 2 * DD, nullptr, nullptr, h0, noise_s,
      out, nullptr, nullptr, out, 2);
}

// Round 3
// 786.676 us; speedup vs baseline: 4.5959x; 1.3803x over previous
//
#include <hip/hip_runtime.h>
#include <stdint.h>
#include <math.h>

// Problem constants (fixed by reference setup_inputs)
#define B_SZ   32
#define T_LEN  2048
#define DIN    512
#define DD     512
#define M_TOT  (B_SZ * T_LEN)   // 65536 rows
#define NTHREADS 256
#define WSZ    ((size_t)DD * DD)

typedef unsigned short u16;
typedef __attribute__((ext_vector_type(8))) short short8;
typedef __attribute__((ext_vector_type(4))) float f32x4;

// ---------------------------------------------------------------------------
// fp32 -> bf16 round-to-nearest-even
// ---------------------------------------------------------------------------
__device__ __forceinline__ u16 f2bf(float f) {
  uint32_t u = __float_as_uint(f);
  uint32_t r = (u + 0x7FFFu + ((u >> 16) & 1u)) >> 16;
  return (u16)r;
}

// async global->LDS, 16B per lane; LDS dest = wave-uniform base + lane*16
typedef const void __attribute__((address_space(1)))* as1cp;
typedef void __attribute__((address_space(3)))* as3p;
__device__ __forceinline__ void async16(const void* g, void* l) {
  __builtin_amdgcn_global_load_lds((as1cp)(uintptr_t)g,
                                   (as3p)(uint32_t)(uintptr_t)l, 16, 0, 0);
}

// ---------------------------------------------------------------------------
// Threefry-2x32 (20 rounds), bit-exact vs JAX's threefry2x32 primitive.
// ---------------------------------------------------------------------------
__device__ __forceinline__ uint32_t rotl32(uint32_t x, int n) {
  return (x << n) | (x >> (32 - n));
}

__device__ __forceinline__ void threefry2x32(uint32_t k0, uint32_t k1,
                                             uint32_t x0, uint32_t x1,
                                             uint32_t& o0, uint32_t& o1) {
  const uint32_t ks0 = k0, ks1 = k1, ks2 = k0 ^ k1 ^ 0x1BD11BDAu;
  uint32_t v0 = x0 + ks0, v1 = x1 + ks1;
#define TF_R(r) { v0 += v1; v1 = rotl32(v1, (r)); v1 ^= v0; }
  TF_R(13) TF_R(15) TF_R(26) TF_R(6)
  v0 += ks1; v1 += ks2 + 1u;
  TF_R(17) TF_R(29) TF_R(16) TF_R(24)
  v0 += ks2; v1 += ks0 + 2u;
  TF_R(13) TF_R(15) TF_R(26) TF_R(6)
  v0 += ks0; v1 += ks1 + 3u;
  TF_R(17) TF_R(29) TF_R(16) TF_R(24)
  v0 += ks1; v1 += ks2 + 4u;
  TF_R(13) TF_R(15) TF_R(26) TF_R(6)
  v0 += ks2; v1 += ks0 + 5u;
#undef TF_R
  o0 = v0; o1 = v1;
}

__device__ __forceinline__ float u01_from_key(uint32_t ka, uint32_t kb, uint32_t idx) {
  uint32_t r0, r1;
  threefry2x32(ka, kb, 0u, idx, r0, r1);
  uint32_t bits = r0 ^ r1;
  return __uint_as_float((bits >> 9) | 0x3F800000u) - 1.0f;
}

__global__ void noise_kernel(float* __restrict__ noise_i, float* __restrict__ noise_s) {
  int i = blockIdx.x * blockDim.x + threadIdx.x;
  if (i >= B_SZ * DIN) return;
  uint32_t k1a, k1b, k2a, k2b;
  threefry2x32(0u, 42u, 0u, 0u, k1a, k1b);
  threefry2x32(0u, 42u, 0u, 1u, k2a, k2b);
  float ui = u01_from_key(k1a, k1b, (uint32_t)i);
  noise_i[i] = (ui < 0.25f) ? 4.0f : 0.0f;
  float us = u01_from_key(k2a, k2b, (uint32_t)i);
  noise_s[i] = (us < 0.75f) ? (1.0f / 0.75f) : 0.0f;
}

// layer-0 state projections, exact fp32 (t-independent):
// vH0[b,c] = sum_k h0[k]*noise_s[b,k]*recurH_w[0][k,c] + recurH_b[0][c]
// grid 64: block = (b, half). Coalesced W reads; sdv staged in LDS.
__global__ __launch_bounds__(256) void vec0_kernel(
    const float* __restrict__ h0, const float* __restrict__ noise_s,
    const float* __restrict__ rHw, const float* __restrict__ rHb,
    const float* __restrict__ rTw, const float* __restrict__ rTb,
    float* __restrict__ vH0, float* __restrict__ vT0) {
  __shared__ float sdv[DD];
  const int b = blockIdx.x >> 1;
  const int c = (blockIdx.x & 1) * 256 + threadIdx.x;
  for (int k = threadIdx.x; k < DD; k += 256)
    sdv[k] = h0[k] * noise_s[b * DD + k];
  __syncthreads();
  float aH = 0.f, aT = 0.f;
  for (int k = 0; k < DD; ++k) {
    float v = sdv[k];
    aH += v * rHw[(size_t)k * DD + c];
    aT += v * rTw[(size_t)k * DD + c];
  }
  vH0[b * DD + c] = aH + rHb[c];
  vT0[b * DD + c] = aT + rTb[c];
}

// ---------------------------------------------------------------------------
// Transpose+convert all six 512x512 fp32 W[k][n] -> bf16 Wt[n][k].
// grid 384 = 6 matrices x 64 tiles of 64x64.
// Wt order: 0=wH 1=wT 2=r1H 3=r1T 4=r2H 5=r2T
// ---------------------------------------------------------------------------
__global__ __launch_bounds__(256) void wt_all(
    const float* __restrict__ wH, const float* __restrict__ wT,
    const float* __restrict__ rHw, const float* __restrict__ rTw,
    u16* __restrict__ Wt) {
  __shared__ float tile[64][68];
  const int which = blockIdx.x >> 6;
  const float* W;
  switch (which) {
    case 0: W = wH; break;
    case 1: W = wT; break;
    case 2: W = rHw + WSZ; break;
    case 3: W = rTw + WSZ; break;
    case 4: W = rHw + 2 * WSZ; break;
    default: W = rTw + 2 * WSZ; break;
  }
  u16* dst = Wt + (size_t)which * WSZ;
  const int tb = blockIdx.x & 63;
  const int kt = (tb >> 3) * 64;
  const int nt = (tb & 7) * 64;
  const int tid = threadIdx.x;
  {
    int r = tid >> 2;
#pragma unroll
    for (int u = 0; u < 4; ++u) {
      int c = ((tid & 3) + u * 4) * 4;
      float4 v = *(const float4*)(W + (size_t)(kt + r) * DD + nt + c);
      tile[r][c] = v.x; tile[r][c + 1] = v.y; tile[r][c + 2] = v.z; tile[r][c + 3] = v.w;
    }
  }
  __syncthreads();
  {
    int n = tid >> 2, seg = (tid & 3) * 16;
    u16 o[16];
#pragma unroll
    for (int u = 0; u < 16; ++u) o[u] = f2bf(tile[seg + u][n]);
    *(uint4*)(dst + (size_t)(nt + n) * DD + kt + seg) = *(const uint4*)o;
    *(uint4*)(dst + (size_t)(nt + n) * DD + kt + seg + 8) = *(const uint4*)(o + 8);
  }
}

// ---------------------------------------------------------------------------
// Xbf[m][k] = bf16(seq[m][k] * noise_i[b][k]);  one thread per 8 elements.
// ---------------------------------------------------------------------------
__global__ __launch_bounds__(256) void xprep(const float* __restrict__ seq,
                                             const float* __restrict__ noise_i,
                                             u16* __restrict__ Xbf) {
  int idx = blockIdx.x * 256 + threadIdx.x;   // 4,194,304 granules of 8
  int row = idx >> 6;
  int k8 = (idx & 63) * 8;
  int b = row >> 11;
  const float* s = seq + (size_t)row * DIN + k8;
  const float* n = noise_i + b * DIN + k8;
  float4 s0 = *(const float4*)s, s1 = *(const float4*)(s + 4);
  float4 n0 = *(const float4*)n, n1 = *(const float4*)(n + 4);
  u16 o[8];
  o[0] = f2bf(s0.x * n0.x); o[1] = f2bf(s0.y * n0.y);
  o[2] = f2bf(s0.z * n0.z); o[3] = f2bf(s0.w * n0.w);
  o[4] = f2bf(s1.x * n1.x); o[5] = f2bf(s1.y * n1.y);
  o[6] = f2bf(s1.z * n1.z); o[7] = f2bf(s1.w * n1.w);
  *(uint4*)(Xbf + (size_t)idx * 8) = *(const uint4*)o;
}

// ---------------------------------------------------------------------------
// Fused layer GEMM: C_tile 128m x 128n, K=512 in 8 chunks of 64.
// Dual accumulators (H and T) share A-fragments. XOR-swizzled LDS so that
// global_load_lds staging is contiguous AND frag ds_read_b128 is conflict-free.
// __launch_bounds__(256, 2): cap unified VGPR+AGPR at 256 -> 2 waves/SIMD
// (128 acc + ~24 ptrs + ~24 frags fits) -> 2 blocks/CU for barrier overlap.
// Epilogue: highway combine, write S (fp32) + SD (bf16) or final out.
// ---------------------------------------------------------------------------
__global__ __launch_bounds__(256, 2) void layer_gemm(
    const u16* __restrict__ Abf,    // [65536][512] bf16 (X' or SD)
    const u16* __restrict__ WtH,    // [512 n][512 k] bf16
    const u16* __restrict__ WtT,
    const float* __restrict__ hbv,  // [512] H bias vec (bH or rHb[l])
    const float* __restrict__ tbv,  // [512] T bias vec
    const float* __restrict__ vH0,  // [32][512] (layer0) or null
    const float* __restrict__ vT0,
    const float* __restrict__ h0,   // [512]
    const float* __restrict__ noise_s, // [32][512]
    const float* Sprev,             // fp32, null for layer0 (may alias Snew/Out)
    float* Snew,                    // fp32 (layers 0,1)
    u16* __restrict__ SDnew,        // bf16 (layers 0,1)
    float* Out,                     // fp32 (layer2)
    int layer) {
  __shared__ u16 lds[24576];        // A:8192, BH:8192, BT:8192 (48 KiB)
  u16* ldsA  = lds;
  u16* ldsBH = lds + 8192;
  u16* ldsBT = lds + 16384;

  const int tid  = threadIdx.x;
  const int lane = tid & 63, wid = tid >> 6;
  const int bid  = blockIdx.x;
  const int m0   = (bid >> 2) * 128;
  const int c0   = (bid & 3) * 128;
  const int bidx = m0 >> 11;            // batch index (tile never crosses b)
  const int q  = lane >> 4, mr = lane & 15;
  const int wqm = wid >> 1, wqn = wid & 1;

  // Per-lane staging addresses. LDS slot s (16B) holds granule (row=s>>3,
  // k8 = (s&7) ^ (row&7)) of the current k-chunk.
  const u16* gA[4]; const u16* gBH[4]; const u16* gBT[4];
  u16* lA[4]; u16* lBH[4]; u16* lBT[4];
#pragma unroll
  for (int t = 0; t < 4; ++t) {
    int s  = wid * 256 + t * 64 + lane;
    int rm = s >> 3;
    int k8 = (s & 7) ^ (rm & 7);
    gA[t]  = Abf + (size_t)(m0 + rm) * DD + k8 * 8;
    gBH[t] = WtH + (size_t)(c0 + rm) * DD + k8 * 8;
    gBT[t] = WtT + (size_t)(c0 + rm) * DD + k8 * 8;
    int lofs = (wid * 256 + t * 64) * 8;
    lA[t] = ldsA + lofs; lBH[t] = ldsBH + lofs; lBT[t] = ldsBT + lofs;
  }

  f32x4 accH[4][4], accT[4][4];
#pragma unroll
  for (int i = 0; i < 4; ++i)
#pragma unroll
    for (int j = 0; j < 4; ++j) {
      accH[i][j] = (f32x4){0.f, 0.f, 0.f, 0.f};
      accT[i][j] = (f32x4){0.f, 0.f, 0.f, 0.f};
    }

  for (int kb = 0; kb < 8; ++kb) {
    __syncthreads();                 // prior chunk's LDS reads complete
    const int ko = kb * 64;          // k advance in elements (=128B)
#pragma unroll
    for (int t = 0; t < 4; ++t) {
      async16(gA[t] + ko,  lA[t]);
      async16(gBH[t] + ko, lBH[t]);
      async16(gBT[t] + ko, lBT[t]);
    }
    __syncthreads();                 // drains vmcnt: LDS filled

#pragma unroll
    for (int ks = 0; ks < 2; ++ks) {
      const int jj = ((((ks << 2) + q) ^ (mr & 7)) << 3); // u16 offset in row
      short8 a[4];
#pragma unroll
      for (int mt = 0; mt < 4; ++mt)
        a[mt] = *(const short8*)(ldsA + (wqm * 64 + mt * 16 + mr) * 64 + jj);
#pragma unroll
      for (int nt = 0; nt < 4; ++nt) {
        int nofs = (wqn * 64 + nt * 16 + mr) * 64 + jj;
        short8 bh = *(const short8*)(ldsBH + nofs);
        short8 bt = *(const short8*)(ldsBT + nofs);
#pragma unroll
        for (int mt = 0; mt < 4; ++mt) {
          accH[mt][nt] = __builtin_amdgcn_mfma_f32_16x16x32_bf16(a[mt], bh, accH[mt][nt], 0, 0, 0);
          accT[mt][nt] = __builtin_amdgcn_mfma_f32_16x16x32_bf16(a[mt], bt, accT[mt][nt], 0, 0, 0);
        }
      }
    }
  }

  // Epilogue. C/D layout: col = lane&15, row = (lane>>4)*4 + reg.
  const int b512 = bidx * DD;
#pragma unroll
  for (int nt = 0; nt < 4; ++nt) {
    const int gc = c0 + wqn * 64 + nt * 16 + mr;
    float hb = hbv[gc], tb = tbv[gc];
    float nsc = 0.f, h0c = 0.f;
    if (layer == 0) {
      hb += vH0[b512 + gc];
      tb += vT0[b512 + gc];
      h0c = h0[gc];
    }
    if (layer < 2) nsc = noise_s[b512 + gc];
#pragma unroll
    for (int mt = 0; mt < 4; ++mt) {
      const int gmb = m0 + wqm * 64 + mt * 16 + q * 4;
#pragma unroll
      for (int r = 0; r < 4; ++r) {
        const size_t o = (size_t)(gmb + r) * DD + gc;
        float sp = (layer == 0) ? h0c : Sprev[o];
        float hg = tanhf(accH[mt][nt][r] + hb);
        float tg = 1.f / (1.f + __expf(-(accT[mt][nt][r] + tb)));
        float sn = (hg - sp) * tg + sp;
        if (layer < 2) {
          Snew[o] = sn;
          SDnew[o] = f2bf(sn * nsc);
        } else {
          Out[o] = sn;
        }
      }
    }
  }
}

// ---------------------------------------------------------------------------
extern "C" void kernel_launch(void* const* d_in, const int* in_sizes, int n_in,
                              void* d_out, int out_size, void* d_ws, size_t ws_size,
                              hipStream_t stream) {
  const float* h0  = (const float*)d_in[0];
  const float* seq = (const float*)d_in[1];
  const float* wH  = (const float*)d_in[2];
  const float* bH  = (const float*)d_in[3];
  const float* wT  = (const float*)d_in[4];
  const float* bT  = (const float*)d_in[5];
  const float* rHw = (const float*)d_in[6];
  const float* rHb = (const float*)d_in[7];
  const float* rTw = (const float*)d_in[8];
  const float* rTb = (const float*)d_in[9];
  float* out = (float*)d_out;

  char* ws = (char*)d_ws;
  float* noise_i = (float*)(ws);                       // 64 KB
  float* noise_s = (float*)(ws + (64 << 10));          // 64 KB
  float* vH0     = (float*)(ws + (128 << 10));         // 64 KB
  float* vT0     = (float*)(ws + (192 << 10));         // 64 KB
  u16* Wt    = (u16*)(ws + (256 << 10));               // 6 x 512 KB
  u16* Xbf   = (u16*)(ws + (4ull << 20));              // 64 MB (also SD1)
  u16* SD0   = (u16*)(ws + (68ull << 20));             // 64 MB

  noise_kernel<<<(B_SZ * DIN + 255) / 256, 256, 0, stream>>>(noise_i, noise_s);
  vec0_kernel<<<64, 256, 0, stream>>>(h0, noise_s, rHw, rHb, rTw, rTb, vH0, vT0);
  wt_all<<<384, 256, 0, stream>>>(wH, wT, rHw, rTw, Wt);
  xprep<<<M_TOT * DIN / 8 / 256, 256, 0, stream>>>(seq, noise_i, Xbf);

  const int NBLK = (M_TOT / 128) * (DD / 128);   // 2048
  // Layer 0: A=Xbf, S->out, SD->SD0
  layer_gemm<<<NBLK, NTHREADS, 0, stream>>>(
      Xbf, Wt + 0 * WSZ, Wt + 1 * WSZ, bH, bT, vH0, vT0, h0, noise_s,
      nullptr, out, SD0, nullptr, 0);
  // Layer 1: A=SD0, Sprev=out, S->out (in place, disjoint per element), SD->Xbf
  layer_gemm<<<NBLK, NTHREADS, 0, stream>>>(
      SD0, Wt + 2 * WSZ, Wt + 3 * WSZ, rHb + DD, rTb + DD, nullptr, nullptr, h0, noise_s,
      out, out, Xbf, nullptr, 1);
  // Layer 2: A=Xbf(SD1), Sprev=out, final -> out
  layer_gemm<<<NBLK, NTHREADS, 0, stream>>>(
      Xbf, Wt + 4 * WSZ, Wt + 5 * WSZ, rHb + 2 * DD, rTb + 2 * DD, nullptr, nullptr, h0, noise_s,
      out, nullptr, nullptr, out, 2);
}